// Round 2
// baseline (98.522 us; speedup 1.0000x reference)
//
#include <hip/hip_runtime.h>
#include <cstdint>
#include <cstddef>
#include <utility>

// ---------------------------------------------------------------------------
// out[8192,32] = x + P(x)[8192,6545] @ W[6545,32]
// v2: LDS-resident f16 deg-2 product table per 32-row tile.
//   Phase 1: block computes d2[row][m] = x_a*x_b (528 per row) into LDS (f16).
//   Phase 2: each wave runs one K-chunk; deg-3 fragment elem = x_f * d2[m]
//            (1 LDS read + 1 f16 mul, static imm offsets); deg-2 = direct read.
//   Per-step hsel divergence (lanes 0-31 lo-half, 32-63 hi-half) -> each
//   monomial computed exactly once. 2-deep B prefetch + sched_barrier(0)
//   bounds register pressure. Block reduces 4 chunk-partials via LDS f32
//   atomics, then 1 atomicAdd/elem into out (pre-initialized with x).
// Grid: 256 mtiles * 4 cgroups = 1024 blocks * 256 thr; wave w -> chunk
// cgroup*4+w. LDS = 40.2 KB -> 3 blocks/CU, ~12 waves/CU.
// ---------------------------------------------------------------------------

#define NF 32
#define NPOLY 6545
#define KPAD 6656
#define CHUNK_K 416
#define STEPS 26        // 416 / 16
#define D2N 528
#define D2STRIDE 530    // halfs; 1060 B/row: /4 = 265 (odd) -> rows hit distinct banks
#define XSTRIDE 34      // halfs; 68 B/row: /4 = 17 (odd)

typedef _Float16 f16x8 __attribute__((ext_vector_type(8)));
typedef _Float16 f16x2 __attribute__((ext_vector_type(2)));
typedef float f32x16 __attribute__((ext_vector_type(16)));

struct Tbl { uint32_t v[KPAD]; };

// entry: (cnt<<18)|(a<<12)|(b<<6)|c ; cnt=0 -> 1.0, 7 -> 0.0 (pad)
constexpr Tbl build_tbl() {
    Tbl t{};
    int k = 0;
    t.v[k++] = (0u << 18);                                   // constant 1
    for (int f = 0; f < NF; ++f)                             // degree 1
        t.v[k++] = (1u << 18) | (uint32_t(f) << 12);
    for (int f = 0; f < NF; ++f)                             // degree 2: x_f*x_m, m<=f
        for (int m = 0; m <= f; ++m)
            t.v[k++] = (2u << 18) | (uint32_t(f) << 12) | (uint32_t(m) << 6);
    for (int f = 0; f < NF; ++f) {                           // degree 3: x_f*d2[m]
        int cnt = (f + 1) * (f + 2) / 2;
        int g = 0, h = 0;
        for (int m = 0; m < cnt; ++m) {
            t.v[k++] = (3u << 18) | (uint32_t(f) << 12) | (uint32_t(g) << 6) | uint32_t(h);
            ++h;
            if (h > g) { ++g; h = 0; }
        }
    }
    while (k < KPAD) t.v[k++] = (7u << 18);                  // zero pad
    return t;
}
constexpr Tbl TBL = build_tbl();

// deg-2 pair list in d2-index order: index f(f+1)/2+m  <->  (a=f, b=m<=f)
struct D2I { uint8_t a[D2N]; uint8_t b[D2N]; };
constexpr D2I build_d2i() {
    D2I t{};
    int k = 0;
    for (int f = 0; f < NF; ++f)
        for (int m = 0; m <= f; ++m) { t.a[k] = (uint8_t)f; t.b[k] = (uint8_t)m; ++k; }
    return t;
}
constexpr D2I D2T = build_d2i();

template<int K> struct EK {
    static constexpr uint32_t e = TBL.v[K];
    static constexpr int cnt = int(e >> 18);
    static constexpr int a = int((e >> 12) & 63);
    static constexpr int b = int((e >> 6) & 63);
    static constexpr int c = int(e & 63);
    static constexpr int pm = (cnt == 3) ? (b * (b + 1) / 2 + c)
                            : (cnt == 2) ? (a * (a + 1) / 2 + b) : 0;
};

template<int K>
__device__ __forceinline__ _Float16 elem(const _Float16* xrow, const _Float16* d2row) {
    using E = EK<K>;
    if constexpr (E::cnt == 0) return (_Float16)1.0f;
    else if constexpr (E::cnt == 1) return xrow[E::a];
    else if constexpr (E::cnt == 2) return d2row[E::pm];
    else if constexpr (E::cnt == 3) return xrow[E::a] * d2row[E::pm];
    else return (_Float16)0.0f;
}

template<int K>   // elements K, K+1 as a packed pair
__device__ __forceinline__ f16x2 pair2(const _Float16* xrow, const _Float16* d2row) {
    using E1 = EK<K>; using E2 = EK<K + 1>;
    if constexpr (E1::cnt == 3 && E2::cnt == 3 && E1::a == E2::a && E2::pm == E1::pm + 1) {
        f16x2 dd = { d2row[E1::pm], d2row[E1::pm + 1] };
        _Float16 xf = xrow[E1::a];
        f16x2 xx = { xf, xf };
        return dd * xx;                      // v_pk_mul_f16
    } else if constexpr (E1::cnt == 2 && E2::cnt == 2 && E2::pm == E1::pm + 1) {
        f16x2 dd = { d2row[E1::pm], d2row[E1::pm + 1] };
        return dd;                           // direct table read, no mul
    } else {
        f16x2 r = { elem<K>(xrow, d2row), elem<K + 1>(xrow, d2row) };
        return r;
    }
}

template<int KB>  // 8 elements KB..KB+7 -> A-fragment half
__device__ __forceinline__ f16x8 gen8(const _Float16* xrow, const _Float16* d2row) {
    f16x2 p0 = pair2<KB + 0>(xrow, d2row);
    f16x2 p1 = pair2<KB + 2>(xrow, d2row);
    f16x2 p2 = pair2<KB + 4>(xrow, d2row);
    f16x2 p3 = pair2<KB + 6>(xrow, d2row);
    f16x8 r;
    r[0] = p0[0]; r[1] = p0[1]; r[2] = p1[0]; r[3] = p1[1];
    r[4] = p2[0]; r[5] = p2[1]; r[6] = p3[0]; r[7] = p3[1];
    return r;
}

template<int CB, int T>
__device__ __forceinline__ f16x8 loadB(const _Float16* __restrict__ Wh, int hsel, int n) {
    constexpr int TG = (CB + T * 16) >> 4;
    return *(const f16x8*)(Wh + ((((TG * 2) + 0) * 32) * 8) + ((hsel * 32 + n) << 3));
}

template<int CB, int... Ts>
__device__ __forceinline__ void chunk_impl(std::integer_sequence<int, Ts...>,
                                           const _Float16* xrow, const _Float16* d2row,
                                           const _Float16* __restrict__ Wh,
                                           int hsel, int n, f32x16& acc) {
    f16x8 bq[2];
    bq[0] = loadB<CB, 0>(Wh, hsel, n);
    bq[1] = loadB<CB, 1>(Wh, hsel, n);
    ([&] {
        constexpr int T = Ts;
        f16x8 b = bq[T & 1];
        if constexpr (T + 2 < STEPS) bq[T & 1] = loadB<CB, T + 2>(Wh, hsel, n);
        constexpr int K0 = CB + T * 16;
        f16x8 a;
        if (hsel == 0) a = gen8<K0>(xrow, d2row);
        else           a = gen8<K0 + 8>(xrow, d2row);
        acc = __builtin_amdgcn_mfma_f32_32x32x16_f16(a, b, acc, 0, 0, 0);
        __builtin_amdgcn_sched_barrier(0);   // cap cross-step hoisting / liveness
    }(), ...);
}

template<int CB>
__device__ __forceinline__ void do_chunk(const _Float16* xrow, const _Float16* d2row,
                                         const _Float16* __restrict__ Wh,
                                         int hsel, int n, f32x16& acc) {
    chunk_impl<CB>(std::make_integer_sequence<int, STEPS>{}, xrow, d2row, Wh, hsel, n, acc);
}

// phase-1 static range: d2row[m] = x_a * x_b for m in [M0, M0+66)
template<int M0, int... Ms>
__device__ __forceinline__ void p1_impl(std::integer_sequence<int, Ms...>,
                                        const float (&xr)[NF], _Float16* d2row) {
    ((d2row[M0 + Ms] = (_Float16)(xr[D2T.a[M0 + Ms]] * xr[D2T.b[M0 + Ms]])), ...);
}

__global__ void init_out(const float4* __restrict__ x, float4* __restrict__ out) {
    int id = blockIdx.x * 256 + threadIdx.x;   // 65536 float4 = 262144 floats
    out[id] = x[id];
}

// Wh layout: [tg][half][n][8 j]; both reads and writes fully coalesced.
__global__ void prep_w(const float* __restrict__ W, _Float16* __restrict__ Wh) {
    int id = blockIdx.x * 256 + threadIdx.x;   // 0 .. 26623
    int n = id & 31;
    int hh = (id >> 5) & 1;
    int tg = id >> 6;
    f16x8 v;
#pragma unroll
    for (int j = 0; j < 8; ++j) {
        int k = tg * 16 + hh * 8 + j;
        float w = (k < NPOLY) ? W[k * 32 + n] : 0.0f;
        v[j] = (_Float16)w;
    }
    *(f16x8*)(Wh + (size_t)id * 8) = v;
}

__global__ __launch_bounds__(256) void gemm(const float* __restrict__ x,
                                            const _Float16* __restrict__ Wh,
                                            float* __restrict__ out) {
    __shared__ __align__(16) _Float16 xh[32 * XSTRIDE];    // 2176 B
    __shared__ __align__(16) _Float16 d2h[32 * D2STRIDE];  // 33920 B
    __shared__ __align__(16) float red[32 * 32];           // 4096 B

    const int tid = threadIdx.x;
    const int wave = tid >> 6;
    const int lane = tid & 63;
    const int hsel = lane >> 5;
    const int n = lane & 31;          // A-row == C-col index for this lane
    const int mtile = blockIdx.x >> 2;
    const int cgroup = blockIdx.x & 3;
    const int chunk = cgroup * 4 + wave;

    // zero the reduction buffer (ordered before any ds-atomic by the barrier)
#pragma unroll
    for (int i = 0; i < 4; ++i) red[tid + i * 256] = 0.0f;

    // ---- phase 1: per-row x (f16) and deg-2 table (f16) ----
    {
        const int prow = tid & 31;
        const int G = tid >> 5;           // 8 groups of 32 threads
        float xr[NF];
        const float4* xp = (const float4*)(x + (size_t)(mtile * 32 + prow) * NF);
#pragma unroll
        for (int i = 0; i < 8; ++i) {
            float4 v = xp[i];
            xr[4 * i + 0] = v.x; xr[4 * i + 1] = v.y;
            xr[4 * i + 2] = v.z; xr[4 * i + 3] = v.w;
        }
        _Float16* xrow_w = xh + prow * XSTRIDE;
#pragma unroll
        for (int i = 0; i < 4; ++i) xrow_w[G * 4 + i] = (_Float16)xr[G * 4 + i];
        _Float16* d2row_w = d2h + prow * D2STRIDE;
        switch (G) {
            case 0: p1_impl<0 * 66>(std::make_integer_sequence<int, 66>{}, xr, d2row_w); break;
            case 1: p1_impl<1 * 66>(std::make_integer_sequence<int, 66>{}, xr, d2row_w); break;
            case 2: p1_impl<2 * 66>(std::make_integer_sequence<int, 66>{}, xr, d2row_w); break;
            case 3: p1_impl<3 * 66>(std::make_integer_sequence<int, 66>{}, xr, d2row_w); break;
            case 4: p1_impl<4 * 66>(std::make_integer_sequence<int, 66>{}, xr, d2row_w); break;
            case 5: p1_impl<5 * 66>(std::make_integer_sequence<int, 66>{}, xr, d2row_w); break;
            case 6: p1_impl<6 * 66>(std::make_integer_sequence<int, 66>{}, xr, d2row_w); break;
            case 7: p1_impl<7 * 66>(std::make_integer_sequence<int, 66>{}, xr, d2row_w); break;
            default: break;
        }
    }
    __syncthreads();

    // ---- phase 2: one K-chunk per wave ----
    const _Float16* xrow = xh + n * XSTRIDE;      // A-row m = lane&31
    const _Float16* d2row = d2h + n * D2STRIDE;

    f32x16 acc;
#pragma unroll
    for (int i = 0; i < 16; ++i) acc[i] = 0.0f;

    switch (chunk) {
        case  0: do_chunk< 0 * CHUNK_K>(xrow, d2row, Wh, hsel, n, acc); break;
        case  1: do_chunk< 1 * CHUNK_K>(xrow, d2row, Wh, hsel, n, acc); break;
        case  2: do_chunk< 2 * CHUNK_K>(xrow, d2row, Wh, hsel, n, acc); break;
        case  3: do_chunk< 3 * CHUNK_K>(xrow, d2row, Wh, hsel, n, acc); break;
        case  4: do_chunk< 4 * CHUNK_K>(xrow, d2row, Wh, hsel, n, acc); break;
        case  5: do_chunk< 5 * CHUNK_K>(xrow, d2row, Wh, hsel, n, acc); break;
        case  6: do_chunk< 6 * CHUNK_K>(xrow, d2row, Wh, hsel, n, acc); break;
        case  7: do_chunk< 7 * CHUNK_K>(xrow, d2row, Wh, hsel, n, acc); break;
        case  8: do_chunk< 8 * CHUNK_K>(xrow, d2row, Wh, hsel, n, acc); break;
        case  9: do_chunk< 9 * CHUNK_K>(xrow, d2row, Wh, hsel, n, acc); break;
        case 10: do_chunk<10 * CHUNK_K>(xrow, d2row, Wh, hsel, n, acc); break;
        case 11: do_chunk<11 * CHUNK_K>(xrow, d2row, Wh, hsel, n, acc); break;
        case 12: do_chunk<12 * CHUNK_K>(xrow, d2row, Wh, hsel, n, acc); break;
        case 13: do_chunk<13 * CHUNK_K>(xrow, d2row, Wh, hsel, n, acc); break;
        case 14: do_chunk<14 * CHUNK_K>(xrow, d2row, Wh, hsel, n, acc); break;
        case 15: do_chunk<15 * CHUNK_K>(xrow, d2row, Wh, hsel, n, acc); break;
        default: break;
    }

    // C/D layout (32x32): col = lane&31, row = (reg&3) + 8*(reg>>2) + 4*hsel
#pragma unroll
    for (int r = 0; r < 16; ++r) {
        int rr = (r & 3) + 8 * (r >> 2) + 4 * hsel;
        atomicAdd(&red[rr * 32 + n], acc[r]);    // ds_add_f32, conflict-free lanes
    }
    __syncthreads();

#pragma unroll
    for (int i = 0; i < 4; ++i) {
        int e = tid + i * 256;                   // 0..1023 over the 32x32 tile
        atomicAdd(out + ((size_t)(mtile * 32 + (e >> 5)) * 32 + (e & 31)), red[e]);
    }
}

extern "C" void kernel_launch(void* const* d_in, const int* in_sizes, int n_in,
                              void* d_out, int out_size, void* d_ws, size_t ws_size,
                              hipStream_t stream) {
    (void)in_sizes; (void)n_in; (void)out_size; (void)ws_size;
    const float* x = (const float*)d_in[0];   // [8192,32]
    const float* W = (const float*)d_in[1];   // [6545,32]
    float* out = (float*)d_out;               // [8192,32]
    _Float16* Wh = (_Float16*)d_ws;           // 6656*32*2 = 425984 B of d_ws

    init_out<<<256, 256, 0, stream>>>((const float4*)x, (float4*)out);
    prep_w<<<104, 256, 0, stream>>>(W, Wh);
    gemm<<<1024, 256, 0, stream>>>(x, Wh, out);
}

// Round 3
// 74.230 us; speedup vs baseline: 1.3273x; 1.3273x over previous
//
#include <hip/hip_runtime.h>
#include <cstdint>
#include <cstddef>
#include <utility>

// ---------------------------------------------------------------------------
// out[8192,32] = x + P(x)[8192,6545] @ W[6545,32]
// v3: ONE tiny uniform K-loop for all waves (no template switch, no I$ blowup).
//   K reordered (W permuted to match) so each MFMA A-octet = 8 consecutive
//   halfs of an LDS table t = [1, x(32), pad(7), d2(528), pad] (576/row,
//   XOR-swizzled in 16B octets -> ds_read_b128 conflict-free & aligned).
//   Per half-step descriptor (toff,xidx) from a compile-time table, fetched
//   as uniform s_load_dwordx2; A = t-octet * x[xidx] via 4 v_pk_mul_f16.
//   B (Wh f16, permuted) register-prefetched 2 deep, global dwordx4.
//   Chunks: 417 steps split 16 ways; grid 256 mtiles x 4 cgroups; wave w of
//   block handles chunk cg*4+w. Block reduces 4 partials in LDS (aliased over
//   t), then atomicAdd into out (pre-initialized with x by prep kernel).
// LDS 39040 B -> 4 blocks/CU, 16 waves/CU.
// ---------------------------------------------------------------------------

#define NF 32
#define NPOLY 6545
#define NSTEPS 417          // K = 6672 = 417*16
#define NOCT 834            // 2 half-octets per step
#define TSTRIDE 576         // halfs per t-row (72 octets)
#define D2OFF 40            // d2 base index inside t (8-aligned)
#define XDSTRIDE 34         // halfs per xdup row (17 words, odd -> no conflicts)

typedef _Float16 f16x8 __attribute__((ext_vector_type(8)));
typedef float f32x16 __attribute__((ext_vector_type(16)));

#define D2N 528
struct D2I { uint8_t a[D2N]; uint8_t b[D2N]; };
constexpr D2I build_d2i() {
    D2I t{};
    int k = 0;
    for (int f = 0; f < NF; ++f)
        for (int m = 0; m <= f; ++m) { t.a[k] = (uint8_t)f; t.b[k] = (uint8_t)m; ++k; }
    return t;
}
constexpr D2I D2T = build_d2i();

// Descriptor per half-octet: toff (low 16) | xidx<<16.  xidx: 0 -> 1.0, 1+f -> x_f.
struct Desc { uint32_t d[NOCT]; };
constexpr Desc build_desc() {
    Desc D{};
    int u = 0;
    for (int o = 0; o < 72; ++o)                       // segA: direct reads of t
        D.d[u++] = (uint32_t)(o * 8);                  // xidx = 0 (mul by 1.0)
    for (int f = 0; f < NF; ++f) {                     // segB: deg-3 = x_f * d2[..]
        int cnt = (f + 1) * (f + 2) / 2;
        for (int j8 = 0; j8 < (cnt + 7) / 8; ++j8)
            D.d[u++] = (uint32_t)(D2OFF + 8 * j8) | ((uint32_t)(1 + f) << 16);
    }
    return D;   // u == 834
}
__device__ const Desc DESC_G = build_desc();

// Map new K index -> original monomial index (or -1 = zero-pad W row).
struct Oldk { int16_t v[NSTEPS * 16]; };
constexpr Oldk build_oldk() {
    Oldk K{};
    int k = 0;
    for (int ti = 0; ti < 576; ++ti) {                 // segA: t-index ti
        int old;
        if (ti == 0) old = 0;
        else if (ti <= 32) old = ti;                   // x_{ti-1}
        else if (ti >= D2OFF && ti < D2OFF + D2N) old = 33 + (ti - D2OFF);
        else old = -1;
        K.v[k++] = (int16_t)old;
    }
    for (int f = 0; f < NF; ++f) {                     // segB
        int cnt = (f + 1) * (f + 2) / 2;
        int off3 = 0;
        for (int g = 0; g < f; ++g) off3 += (g + 1) * (g + 2) / 2;
        int oc = (cnt + 7) / 8;
        for (int m = 0; m < oc * 8; ++m)
            K.v[k++] = (int16_t)(m < cnt ? 561 + off3 + m : -1);
    }
    return K;   // k == 6672
}
__device__ const Oldk OLDK_G = build_oldk();

// ---- phase-1 helpers: value of t[TI] from the lane's x row ----
template<int TI>
__device__ __forceinline__ _Float16 tval(const float (&xr)[NF]) {
    if constexpr (TI == 0) return (_Float16)1.0f;
    else if constexpr (TI >= 1 && TI <= 32) return (_Float16)xr[TI - 1];
    else if constexpr (TI >= D2OFF && TI < D2OFF + D2N) {
        constexpr int m = TI - D2OFF;
        return (_Float16)(xr[D2T.a[m]] * xr[D2T.b[m]]);
    } else return (_Float16)0.0f;
}

template<int O, int... Js>
__device__ __forceinline__ void put_oct(std::integer_sequence<int, Js...>,
                                        const float (&xr)[NF], _Float16* trow, int r) {
    f16x8 v = { tval<O * 8 + Js>(xr)... };
    int slot = (O & ~7) | ((O ^ r) & 7);               // XOR swizzle (16B granule)
    *(f16x8*)(trow + slot * 8) = v;
}

template<int V>
__device__ __forceinline__ void xdw(const float (&xr)[NF], _Float16* xdrow) {
    if constexpr (V == 0) xdrow[0] = (_Float16)1.0f;
    else xdrow[V] = (_Float16)xr[V - 1];
}

template<int G, int... Os>
__device__ __forceinline__ void p1_group(std::integer_sequence<int, Os...>,
                                         const float (&xr)[NF], _Float16* trow,
                                         _Float16* xdrow, int r) {
    (put_oct<9 * G + Os>(std::make_integer_sequence<int, 8>{}, xr, trow, r), ...);
    xdw<4 * G + 0>(xr, xdrow); xdw<4 * G + 1>(xr, xdrow);
    xdw<4 * G + 2>(xr, xdrow); xdw<4 * G + 3>(xr, xdrow);
    if constexpr (G == 7) xdw<32>(xr, xdrow);
}

// ---- prep: out = x  and  Wh = permuted/padded f16 W ----
__global__ void prep(const float* __restrict__ x, const float* __restrict__ W,
                     float* __restrict__ out, _Float16* __restrict__ Wh) {
    int b = blockIdx.x;
    if (b < 256) {
        int id = b * 256 + threadIdx.x;                // 65536 float4
        ((float4*)out)[id] = ((const float4*)x)[id];
    } else {
        int id = (b - 256) * 256 + threadIdx.x;        // octet index
        if (id < NSTEPS * 2 * 32) {                    // 26688
            int step = id >> 6, rem = id & 63, hs = rem >> 5, n = rem & 31;
            int k0 = step * 16 + hs * 8;
            f16x8 v;
#pragma unroll
            for (int j = 0; j < 8; ++j) {
                int old = OLDK_G.v[k0 + j];
                v[j] = (_Float16)(old >= 0 ? W[old * 32 + n] : 0.0f);
            }
            *(f16x8*)(Wh + (size_t)id * 8) = v;
        }
    }
}

__global__ __launch_bounds__(256) void gemm(const float* __restrict__ x,
                                            const _Float16* __restrict__ Wh,
                                            float* __restrict__ out) {
    __shared__ __align__(16) unsigned char smem[39040];
    _Float16* t  = (_Float16*)smem;                    // 32*576 halfs = 36864 B
    _Float16* xd = (_Float16*)(smem + 36864);          // 32*34 halfs = 2176 B
    float* red   = (float*)smem;                       // aliases t after sync (16 KB)

    const int tid = threadIdx.x;
    const int wave = tid >> 6, lane = tid & 63;
    const int hsel = lane >> 5, r = lane & 31;
    const int mtile = blockIdx.x >> 2, cg = blockIdx.x & 3;

    // ---- phase 1: build t (swizzled) + xdup for 32 rows ----
    {
        const int pr = tid & 31, g = tid >> 5;
        float xr[NF];
        const float4* xp = (const float4*)(x + (size_t)(mtile * 32 + pr) * NF);
#pragma unroll
        for (int i = 0; i < 8; ++i) {
            float4 v = xp[i];
            xr[4 * i + 0] = v.x; xr[4 * i + 1] = v.y;
            xr[4 * i + 2] = v.z; xr[4 * i + 3] = v.w;
        }
        _Float16* trow = t + pr * TSTRIDE;
        _Float16* xdrow = xd + pr * XDSTRIDE;
        switch (g) {
            case 0: p1_group<0>(std::make_integer_sequence<int, 9>{}, xr, trow, xdrow, pr); break;
            case 1: p1_group<1>(std::make_integer_sequence<int, 9>{}, xr, trow, xdrow, pr); break;
            case 2: p1_group<2>(std::make_integer_sequence<int, 9>{}, xr, trow, xdrow, pr); break;
            case 3: p1_group<3>(std::make_integer_sequence<int, 9>{}, xr, trow, xdrow, pr); break;
            case 4: p1_group<4>(std::make_integer_sequence<int, 9>{}, xr, trow, xdrow, pr); break;
            case 5: p1_group<5>(std::make_integer_sequence<int, 9>{}, xr, trow, xdrow, pr); break;
            case 6: p1_group<6>(std::make_integer_sequence<int, 9>{}, xr, trow, xdrow, pr); break;
            default: p1_group<7>(std::make_integer_sequence<int, 9>{}, xr, trow, xdrow, pr); break;
        }
    }
    __syncthreads();

    // ---- phase 2: uniform dynamic K-loop, one chunk per wave ----
    const int c = cg * 4 + wave;
    const int s0 = __builtin_amdgcn_readfirstlane((c * NSTEPS) >> 4);
    const int s1 = __builtin_amdgcn_readfirstlane(((c + 1) * NSTEPS) >> 4);
    const _Float16* trow = t + r * TSTRIDE;
    const _Float16* xdrow = xd + r * XDSTRIDE;
    const _Float16* wp = Wh + (size_t)lane * 8;        // + s*512 halfs per step

    f32x16 acc;
#pragma unroll
    for (int i = 0; i < 16; ++i) acc[i] = 0.0f;

    uint32_t dlo = DESC_G.d[2 * s0];                   // uniform -> s_load
    uint32_t dhi = DESC_G.d[2 * s0 + 1];
    f16x8 b0 = *(const f16x8*)(wp + (size_t)s0 * 512);
    f16x8 b1 = *(const f16x8*)(wp + (size_t)(s0 + 1) * 512);

    for (int s = s0; s < s1; ++s) {
        uint32_t d = hsel ? dhi : dlo;
        dlo = DESC_G.d[2 * (s + 1)];
        dhi = DESC_G.d[2 * (s + 1) + 1];
        int toff = (int)(d & 0xffffu);
        int xv = (int)(d >> 16);
        int o = toff >> 3;
        int slot = (o & ~7) | ((o ^ r) & 7);
        f16x8 araw = *(const f16x8*)(trow + slot * 8); // ds_read_b128
        _Float16 xs = xdrow[xv];                       // ds_read_u16
        f16x8 xsv = { xs, xs, xs, xs, xs, xs, xs, xs };
        f16x8 a = araw * xsv;                          // 4x v_pk_mul_f16
        f16x8 bu = b0; b0 = b1;
        b1 = *(const f16x8*)(wp + (size_t)(s + 2) * 512);  // prefetch (over-read ok, unused)
        acc = __builtin_amdgcn_mfma_f32_32x32x16_f16(a, bu, acc, 0, 0, 0);
    }

    // ---- epilogue: per-wave banks in LDS (aliased over t), then global atomics ----
    __syncthreads();                                   // all waves done reading t/xd
    float* bank = red + wave * 1024;
#pragma unroll
    for (int reg = 0; reg < 16; ++reg) {
        int rr = (reg & 3) + 8 * (reg >> 2) + 4 * hsel;
        bank[rr * 32 + r] = acc[reg];
    }
    __syncthreads();
    float* op = out + (size_t)mtile * 1024;
#pragma unroll
    for (int i = 0; i < 4; ++i) {
        int e = tid + i * 256;
        float v = red[e] + red[1024 + e] + red[2048 + e] + red[3072 + e];
        atomicAdd(op + e, v);
    }
}

extern "C" void kernel_launch(void* const* d_in, const int* in_sizes, int n_in,
                              void* d_out, int out_size, void* d_ws, size_t ws_size,
                              hipStream_t stream) {
    (void)in_sizes; (void)n_in; (void)out_size; (void)ws_size;
    const float* x = (const float*)d_in[0];   // [8192,32]
    const float* W = (const float*)d_in[1];   // [6545,32]
    float* out = (float*)d_out;               // [8192,32]
    _Float16* Wh = (_Float16*)d_ws;           // 417*1024 B + prefetch slack

    prep<<<361, 256, 0, stream>>>(x, W, out, Wh);
    gemm<<<1024, 256, 0, stream>>>(x, Wh, out);
}

// Round 4
// 71.003 us; speedup vs baseline: 1.3876x; 1.0454x over previous
//
#include <hip/hip_runtime.h>
#include <cstdint>
#include <cstddef>
#include <utility>

// ---------------------------------------------------------------------------
// out[8192,32] = x + P(x)[8192,6545] @ W[6545,32]
// v4: one block per 32-row mtile (256 blocks x 512 thr / 8 waves).
//   Phase 1 (once per tile): LDS t=[1,x,d2] (XOR-swizzled octets), xdup, and
//   the 842-entry descriptor table (zero-padded -> pipeline over-issue safe).
//   Phase 2: each wave does K/8 (~52 MFMA steps) with a 2-deep ping-pong
//   pipeline: desc(ds_read_b32) -> A-octet(ds_read_b128) + xs(ds_read_u16)
//   + B(global dwordx4), NO scalar memory ops in the loop (DS in-order =>
//   partial lgkmcnt waits), 2 accumulators break the MFMA chain.
//   Epilogue: 8-bank LDS reduce (aliased over t), direct store out = x + sum.
//   No atomics, no init kernel. LDS 42.5 KB.
// ---------------------------------------------------------------------------

#define NF 32
#define NPOLY 6545
#define NSTEPS 417          // K = 6672 = 417*16
#define NOCT 834            // 2 half-octets per step
#define NDESC 842           // padded (+8 zero entries) for pipeline over-issue
#define TSTRIDE 576         // halfs per t-row (72 octets, 1152 B)
#define D2OFF 40            // d2 base index inside t (8-aligned)
#define XDSTRIDE 34         // halfs per xdup row (68 B, odd word stride)

#define T_BYTES   36864     // 32*576*2
#define XD_OFF    36864
#define XD_BYTES  2176      // 32*34*2
#define DESC_OFF  39040
#define DESC_BYTES 3368     // 842*4
#define SMEM_BYTES 42496

typedef _Float16 f16x8 __attribute__((ext_vector_type(8)));
typedef float f32x16 __attribute__((ext_vector_type(16)));

#define D2N 528
struct D2I { uint8_t a[D2N]; uint8_t b[D2N]; };
constexpr D2I build_d2i() {
    D2I t{};
    int k = 0;
    for (int f = 0; f < NF; ++f)
        for (int m = 0; m <= f; ++m) { t.a[k] = (uint8_t)f; t.b[k] = (uint8_t)m; ++k; }
    return t;
}
constexpr D2I D2T = build_d2i();

// Descriptor per half-octet: low16 = t byte offset (16B aligned), high16 = xd
// byte offset (xidx*2; xidx 0 -> 1.0, 1+f -> x_f).
struct Desc { uint32_t d[NOCT]; };
constexpr Desc build_desc() {
    Desc D{};
    int u = 0;
    for (int o = 0; o < 72; ++o)                       // segA: direct t octets
        D.d[u++] = (uint32_t)(o * 16);
    for (int f = 0; f < NF; ++f) {                     // segB: x_f * d2 octets
        int cnt = (f + 1) * (f + 2) / 2;
        for (int j8 = 0; j8 < (cnt + 7) / 8; ++j8)
            D.d[u++] = (uint32_t)((D2OFF + 8 * j8) * 2) | ((uint32_t)((1 + f) * 2) << 16);
    }
    return D;   // u == 834
}
__device__ const Desc DESC_G = build_desc();

// Map new K index -> original monomial index (or -1 = zero W row).
struct Oldk { int16_t v[NSTEPS * 16]; };
constexpr Oldk build_oldk() {
    Oldk K{};
    int k = 0;
    for (int ti = 0; ti < 576; ++ti) {                 // segA
        int old;
        if (ti == 0) old = 0;
        else if (ti <= 32) old = ti;
        else if (ti >= D2OFF && ti < D2OFF + D2N) old = 33 + (ti - D2OFF);
        else old = -1;
        K.v[k++] = (int16_t)old;
    }
    for (int f = 0; f < NF; ++f) {                     // segB
        int cnt = (f + 1) * (f + 2) / 2;
        int off3 = 0;
        for (int g = 0; g < f; ++g) off3 += (g + 1) * (g + 2) / 2;
        int oc = (cnt + 7) / 8;
        for (int m = 0; m < oc * 8; ++m)
            K.v[k++] = (int16_t)(m < cnt ? 561 + off3 + m : -1);
    }
    return K;   // k == 6672
}
__device__ const Oldk OLDK_G = build_oldk();

// ---- phase-1 helpers ----
template<int TI>
__device__ __forceinline__ _Float16 tval(const float (&xr)[NF]) {
    if constexpr (TI == 0) return (_Float16)1.0f;
    else if constexpr (TI >= 1 && TI <= 32) return (_Float16)xr[TI - 1];
    else if constexpr (TI >= D2OFF && TI < D2OFF + D2N) {
        constexpr int m = TI - D2OFF;
        return (_Float16)(xr[D2T.a[m]] * xr[D2T.b[m]]);
    } else return (_Float16)0.0f;
}

template<int O, int... Js>
__device__ __forceinline__ void put_oct(std::integer_sequence<int, Js...>,
                                        const float (&xr)[NF], _Float16* trow, int r) {
    f16x8 v = { tval<O * 8 + Js>(xr)... };
    int slot = (O & ~7) | ((O ^ r) & 7);               // XOR swizzle (16B granule)
    *(f16x8*)(trow + slot * 8) = v;
}

template<int BASE, int... Os>
__device__ __forceinline__ void p1_octs(std::integer_sequence<int, Os...>,
                                        const float (&xr)[NF], _Float16* trow, int r) {
    (put_oct<BASE + Os>(std::make_integer_sequence<int, 8>{}, xr, trow, r), ...);
}

template<int V>
__device__ __forceinline__ void xdw(const float (&xr)[NF], _Float16* xdrow) {
    if constexpr (V == 0) xdrow[0] = (_Float16)1.0f;
    else if constexpr (V <= 32) xdrow[V] = (_Float16)xr[V - 1];
}

template<int G>
__device__ __forceinline__ void p1_group(const float (&xr)[NF], _Float16* trow,
                                         _Float16* xdrow, int r) {
    if constexpr (G < 8)
        p1_octs<G * 5>(std::make_integer_sequence<int, 5>{}, xr, trow, r);
    else
        p1_octs<40 + (G - 8) * 4>(std::make_integer_sequence<int, 4>{}, xr, trow, r);
    xdw<2 * G>(xr, xdrow);
    xdw<2 * G + 1>(xr, xdrow);
    if constexpr (G == 15) xdw<32>(xr, xdrow);
}

// ---- prep: Wh = permuted/padded f16 W (layout [step][64 lanes][8]) ----
__global__ void prep(const float* __restrict__ W, _Float16* __restrict__ Wh) {
    int id = blockIdx.x * 256 + threadIdx.x;           // octet index
    if (id < NSTEPS * 64) {                            // 26688
        int step = id >> 6, rem = id & 63, hs = rem >> 5, n = rem & 31;
        int k0 = step * 16 + hs * 8;
        f16x8 v;
#pragma unroll
        for (int j = 0; j < 8; ++j) {
            int old = OLDK_G.v[k0 + j];
            v[j] = (_Float16)(old >= 0 ? W[old * 32 + n] : 0.0f);
        }
        *(f16x8*)(Wh + (size_t)id * 8) = v;
    }
}

__global__ __launch_bounds__(512, 2) void gemm(const float* __restrict__ x,
                                               const _Float16* __restrict__ Wh,
                                               float* __restrict__ out) {
    __shared__ __align__(16) unsigned char smem[SMEM_BYTES];
    _Float16* t  = (_Float16*)smem;
    _Float16* xd = (_Float16*)(smem + XD_OFF);
    uint32_t* descL = (uint32_t*)(smem + DESC_OFF);

    const int tid = threadIdx.x;
    const int wave = __builtin_amdgcn_readfirstlane(tid >> 6);
    const int lane = tid & 63;
    const int hsel = lane >> 5, r = lane & 31;
    const int mtile = blockIdx.x;

    // ---- phase 1: t (swizzled), xdup, and descriptor copy ----
    {
        const int pr = tid & 31, g = tid >> 5;         // 16 workers per row
        float xr[NF];
        const float4* xp = (const float4*)(x + (size_t)(mtile * 32 + pr) * NF);
#pragma unroll
        for (int i = 0; i < 8; ++i) {
            float4 v = xp[i];
            xr[4 * i + 0] = v.x; xr[4 * i + 1] = v.y;
            xr[4 * i + 2] = v.z; xr[4 * i + 3] = v.w;
        }
        _Float16* trow = t + pr * TSTRIDE;
        _Float16* xdrow = xd + pr * XDSTRIDE;
        switch (g) {
            case  0: p1_group< 0>(xr, trow, xdrow, pr); break;
            case  1: p1_group< 1>(xr, trow, xdrow, pr); break;
            case  2: p1_group< 2>(xr, trow, xdrow, pr); break;
            case  3: p1_group< 3>(xr, trow, xdrow, pr); break;
            case  4: p1_group< 4>(xr, trow, xdrow, pr); break;
            case  5: p1_group< 5>(xr, trow, xdrow, pr); break;
            case  6: p1_group< 6>(xr, trow, xdrow, pr); break;
            case  7: p1_group< 7>(xr, trow, xdrow, pr); break;
            case  8: p1_group< 8>(xr, trow, xdrow, pr); break;
            case  9: p1_group< 9>(xr, trow, xdrow, pr); break;
            case 10: p1_group<10>(xr, trow, xdrow, pr); break;
            case 11: p1_group<11>(xr, trow, xdrow, pr); break;
            case 12: p1_group<12>(xr, trow, xdrow, pr); break;
            case 13: p1_group<13>(xr, trow, xdrow, pr); break;
            case 14: p1_group<14>(xr, trow, xdrow, pr); break;
            default: p1_group<15>(xr, trow, xdrow, pr); break;
        }
#pragma unroll
        for (int i = tid; i < NDESC; i += 512)
            descL[i] = (i < NOCT) ? DESC_G.d[i] : 0u;  // zero pad = safe addrs
    }
    __syncthreads();

    // ---- phase 2: 2-deep ping-pong pipelined K-loop, one chunk per wave ----
    const int s0 = __builtin_amdgcn_readfirstlane((wave * NSTEPS) >> 3);
    const int s1 = __builtin_amdgcn_readfirstlane(((wave + 1) * NSTEPS) >> 3);
    const char* trowB = (const char*)t + r * (TSTRIDE * 2);
    const char* xdrowB = (const char*)xd + r * (XDSTRIDE * 2);
    const char* wpB = (const char*)Wh + lane * 16;     // + s*1024 per step
    const uint32_t rx = (uint32_t)((r & 7) << 4);

    f32x16 acc0, acc1;
#pragma unroll
    for (int i = 0; i < 16; ++i) { acc0[i] = 0.0f; acc1[i] = 0.0f; }

    uint32_t dva = descL[2 * s0 + hsel];
    uint32_t dvb = descL[2 * s0 + 2 + hsel];
    f16x8 araw0 = *(const f16x8*)(trowB + ((dva & 0xffffu) ^ rx));
    _Float16 xs0 = *(const _Float16*)(xdrowB + (dva >> 16));
    f16x8 araw1 = *(const f16x8*)(trowB + ((dvb & 0xffffu) ^ rx));
    _Float16 xs1 = *(const _Float16*)(xdrowB + (dvb >> 16));
    uint32_t dval0 = descL[2 * (s0 + 2) + hsel];
    uint32_t dval1 = descL[2 * (s0 + 3) + hsel];
    f16x8 breg0 = *(const f16x8*)(wpB + (size_t)s0 * 1024);
    f16x8 breg1 = *(const f16x8*)(wpB + (size_t)(s0 + 1) * 1024);

#define BODY(P, SCUR) do {                                                    \
    uint32_t d_ = dval##P;                                                    \
    f16x8 xsv_ = { xs##P, xs##P, xs##P, xs##P, xs##P, xs##P, xs##P, xs##P };  \
    f16x8 a_ = araw##P * xsv_;                                                \
    f16x8 bu_ = breg##P;                                                      \
    araw##P = *(const f16x8*)(trowB + ((d_ & 0xffffu) ^ rx));                 \
    xs##P   = *(const _Float16*)(xdrowB + (d_ >> 16));                        \
    dval##P = descL[2 * ((SCUR) + 4) + hsel];                                 \
    breg##P = *(const f16x8*)(wpB + (size_t)((SCUR) + 2) * 1024);             \
    acc##P = __builtin_amdgcn_mfma_f32_32x32x16_f16(a_, bu_, acc##P, 0, 0, 0);\
} while (0)

    int s = s0;
    for (; s + 1 < s1; s += 2) { BODY(0, s); BODY(1, s + 1); }
    if (s < s1) {   // odd-length chunk tail (slot 0)
        f16x8 xsv_ = { xs0, xs0, xs0, xs0, xs0, xs0, xs0, xs0 };
        f16x8 a_ = araw0 * xsv_;
        acc0 = __builtin_amdgcn_mfma_f32_32x32x16_f16(a_, breg0, acc0, 0, 0, 0);
    }
#undef BODY

    // ---- epilogue: 8-bank LDS reduce (aliased over t), direct store ----
    __syncthreads();                                   // all waves done with t/xd
    float* red = (float*)smem;                         // 8 * 4096 B = 32768 <= T_BYTES
    float* bank = red + wave * 1024;
#pragma unroll
    for (int reg = 0; reg < 16; ++reg) {
        int rr = (reg & 3) + 8 * (reg >> 2) + 4 * hsel;  // C/D row
        bank[rr * 32 + r] = acc0[reg] + acc1[reg];
    }
    __syncthreads();
    const float* xg = x + (size_t)mtile * 1024;
    float* op = out + (size_t)mtile * 1024;
#pragma unroll
    for (int i = 0; i < 2; ++i) {
        int e = tid + i * 512;
        float v = red[e] + red[1024 + e] + red[2048 + e] + red[3072 + e]
                + red[4096 + e] + red[5120 + e] + red[6144 + e] + red[7168 + e];
        op[e] = xg[e] + v;
    }
}

extern "C" void kernel_launch(void* const* d_in, const int* in_sizes, int n_in,
                              void* d_out, int out_size, void* d_ws, size_t ws_size,
                              hipStream_t stream) {
    (void)in_sizes; (void)n_in; (void)out_size; (void)ws_size;
    const float* x = (const float*)d_in[0];   // [8192,32]
    const float* W = (const float*)d_in[1];   // [6545,32]
    float* out = (float*)d_out;               // [8192,32]
    _Float16* Wh = (_Float16*)d_ws;           // ~430 KB of d_ws used

    prep<<<105, 256, 0, stream>>>(W, Wh);
    gemm<<<256, 512, 0, stream>>>(x, Wh, out);
}

// Round 5
// 69.974 us; speedup vs baseline: 1.4080x; 1.0147x over previous
//
#include <hip/hip_runtime.h>
#include <cstdint>
#include <cstddef>
#include <utility>

// ---------------------------------------------------------------------------
// out[8192,32] = x + P(x)[8192,6545] @ W[6545,32]
// v5: occupancy + latency-chain fix over v4.
//   Grid 512 x 512thr: 2 blocks per 32-row mtile (K-split 2) -> 2 blocks/CU,
//   16 waves/CU. Each wave: ~26 MFMA steps (c = kh*8+wave of 16 chunks).
//   Descriptors: preloaded into 2 VGPRs per wave (lane=step), consumed via
//   v_readlane + cndmask -- no desc LDS reads, no desc address math.
//   Per step: A-octet ds_read_b128 (XOR-swizzled t), xs ds_read_u16,
//   B global dwordx4 (2-deep prefetch), 4x v_pk_mul_f16, 1 MFMA, 2 accs.
//   Epilogue: 8-bank LDS reduce (aliased over t) + atomicAdd into out
//   (out pre-initialized with x by prep). LDS 39 KB.
// ---------------------------------------------------------------------------

#define NF 32
#define NPOLY 6545
#define NSTEPS 417          // K = 6672 = 417*16
#define NOCT 834            // 2 half-octets per step
#define NDESC 1024          // padded with zeros (safe over-read addresses)
#define TSTRIDE 576         // halfs per t-row (72 octets, 1152 B)
#define D2OFF 40            // d2 base index inside t (8-aligned)
#define XDSTRIDE 34         // halfs per xdup row (68 B)

#define T_BYTES   36864     // 32*576*2
#define XD_OFF    36864
#define SMEM_BYTES 39040    // t + xd

typedef _Float16 f16x8 __attribute__((ext_vector_type(8)));
typedef float f32x16 __attribute__((ext_vector_type(16)));

#define D2N 528
struct D2I { uint8_t a[D2N]; uint8_t b[D2N]; };
constexpr D2I build_d2i() {
    D2I t{};
    int k = 0;
    for (int f = 0; f < NF; ++f)
        for (int m = 0; m <= f; ++m) { t.a[k] = (uint8_t)f; t.b[k] = (uint8_t)m; ++k; }
    return t;
}
constexpr D2I D2T = build_d2i();

// Descriptor per half-octet: low16 = t byte offset (16B aligned), high16 = xd
// byte offset (xidx*2; xidx 0 -> 1.0, 1+f -> x_f). Zero-padded to NDESC.
struct Desc { uint32_t d[NDESC]; };
constexpr Desc build_desc() {
    Desc D{};
    int u = 0;
    for (int o = 0; o < 72; ++o)                       // segA: direct t octets
        D.d[u++] = (uint32_t)(o * 16);
    for (int f = 0; f < NF; ++f) {                     // segB: x_f * d2 octets
        int cnt = (f + 1) * (f + 2) / 2;
        for (int j8 = 0; j8 < (cnt + 7) / 8; ++j8)
            D.d[u++] = (uint32_t)((D2OFF + 8 * j8) * 2) | ((uint32_t)((1 + f) * 2) << 16);
    }
    while (u < NDESC) D.d[u++] = 0u;                   // toff=0/xoff=0 -> safe
    return D;
}
__device__ const Desc DESC_G = build_desc();

// Map new K index -> original monomial index (or -1 = zero W row).
struct Oldk { int16_t v[NSTEPS * 16]; };
constexpr Oldk build_oldk() {
    Oldk K{};
    int k = 0;
    for (int ti = 0; ti < 576; ++ti) {                 // segA
        int old;
        if (ti == 0) old = 0;
        else if (ti <= 32) old = ti;
        else if (ti >= D2OFF && ti < D2OFF + D2N) old = 33 + (ti - D2OFF);
        else old = -1;
        K.v[k++] = (int16_t)old;
    }
    for (int f = 0; f < NF; ++f) {                     // segB
        int cnt = (f + 1) * (f + 2) / 2;
        int off3 = 0;
        for (int g = 0; g < f; ++g) off3 += (g + 1) * (g + 2) / 2;
        int oc = (cnt + 7) / 8;
        for (int m = 0; m < oc * 8; ++m)
            K.v[k++] = (int16_t)(m < cnt ? 561 + off3 + m : -1);
    }
    return K;
}
__device__ const Oldk OLDK_G = build_oldk();

// ---- phase-1 helpers ----
template<int TI>
__device__ __forceinline__ _Float16 tval(const float (&xr)[NF]) {
    if constexpr (TI == 0) return (_Float16)1.0f;
    else if constexpr (TI >= 1 && TI <= 32) return (_Float16)xr[TI - 1];
    else if constexpr (TI >= D2OFF && TI < D2OFF + D2N) {
        constexpr int m = TI - D2OFF;
        return (_Float16)(xr[D2T.a[m]] * xr[D2T.b[m]]);
    } else return (_Float16)0.0f;
}

template<int O, int... Js>
__device__ __forceinline__ void put_oct(std::integer_sequence<int, Js...>,
                                        const float (&xr)[NF], _Float16* trow, int r) {
    f16x8 v = { tval<O * 8 + Js>(xr)... };
    int slot = (O & ~7) | ((O ^ r) & 7);               // XOR swizzle (16B granule)
    *(f16x8*)(trow + slot * 8) = v;
}

template<int BASE, int... Os>
__device__ __forceinline__ void p1_octs(std::integer_sequence<int, Os...>,
                                        const float (&xr)[NF], _Float16* trow, int r) {
    (put_oct<BASE + Os>(std::make_integer_sequence<int, 8>{}, xr, trow, r), ...);
}

template<int V>
__device__ __forceinline__ void xdw(const float (&xr)[NF], _Float16* xdrow) {
    if constexpr (V == 0) xdrow[0] = (_Float16)1.0f;
    else if constexpr (V <= 32) xdrow[V] = (_Float16)xr[V - 1];
}

template<int G>
__device__ __forceinline__ void p1_group(const float (&xr)[NF], _Float16* trow,
                                         _Float16* xdrow, int r) {
    if constexpr (G < 8)
        p1_octs<G * 5>(std::make_integer_sequence<int, 5>{}, xr, trow, r);
    else
        p1_octs<40 + (G - 8) * 4>(std::make_integer_sequence<int, 4>{}, xr, trow, r);
    xdw<2 * G>(xr, xdrow);
    xdw<2 * G + 1>(xr, xdrow);
    if constexpr (G == 15) xdw<32>(xr, xdrow);
}

// ---- prep: out = x, and Wh = permuted/padded f16 W ([step][64 lanes][8]) ----
__global__ void prep(const float* __restrict__ x, const float* __restrict__ W,
                     float* __restrict__ out, _Float16* __restrict__ Wh) {
    int b = blockIdx.x;
    if (b < 256) {
        int id = b * 256 + threadIdx.x;                // 65536 float4
        ((float4*)out)[id] = ((const float4*)x)[id];
    } else {
        int id = (b - 256) * 256 + threadIdx.x;        // octet index
        if (id < NSTEPS * 64) {                        // 26688
            int step = id >> 6, rem = id & 63, hs = rem >> 5, n = rem & 31;
            int k0 = step * 16 + hs * 8;
            f16x8 v;
#pragma unroll
            for (int j = 0; j < 8; ++j) {
                int old = OLDK_G.v[k0 + j];
                v[j] = (_Float16)(old >= 0 ? W[old * 32 + n] : 0.0f);
            }
            *(f16x8*)(Wh + (size_t)id * 8) = v;
        }
    }
}

__global__ __launch_bounds__(512, 2) void gemm(const float* __restrict__ x,
                                               const _Float16* __restrict__ Wh,
                                               float* __restrict__ out) {
    __shared__ __align__(16) unsigned char smem[SMEM_BYTES];
    _Float16* t  = (_Float16*)smem;
    _Float16* xd = (_Float16*)(smem + XD_OFF);

    const int tid = threadIdx.x;
    const int wave = __builtin_amdgcn_readfirstlane(tid >> 6);
    const int lane = tid & 63;
    const int hsel = lane >> 5, r = lane & 31;
    const int mtile = blockIdx.x >> 1;
    const int kh = blockIdx.x & 1;

    // ---- phase 1: t (swizzled) + xdup ----
    {
        const int pr = tid & 31, g = tid >> 5;         // 16 workers per row
        float xr[NF];
        const float4* xp = (const float4*)(x + (size_t)(mtile * 32 + pr) * NF);
#pragma unroll
        for (int i = 0; i < 8; ++i) {
            float4 v = xp[i];
            xr[4 * i + 0] = v.x; xr[4 * i + 1] = v.y;
            xr[4 * i + 2] = v.z; xr[4 * i + 3] = v.w;
        }
        _Float16* trow = t + pr * TSTRIDE;
        _Float16* xdrow = xd + pr * XDSTRIDE;
        switch (g) {
            case  0: p1_group< 0>(xr, trow, xdrow, pr); break;
            case  1: p1_group< 1>(xr, trow, xdrow, pr); break;
            case  2: p1_group< 2>(xr, trow, xdrow, pr); break;
            case  3: p1_group< 3>(xr, trow, xdrow, pr); break;
            case  4: p1_group< 4>(xr, trow, xdrow, pr); break;
            case  5: p1_group< 5>(xr, trow, xdrow, pr); break;
            case  6: p1_group< 6>(xr, trow, xdrow, pr); break;
            case  7: p1_group< 7>(xr, trow, xdrow, pr); break;
            case  8: p1_group< 8>(xr, trow, xdrow, pr); break;
            case  9: p1_group< 9>(xr, trow, xdrow, pr); break;
            case 10: p1_group<10>(xr, trow, xdrow, pr); break;
            case 11: p1_group<11>(xr, trow, xdrow, pr); break;
            case 12: p1_group<12>(xr, trow, xdrow, pr); break;
            case 13: p1_group<13>(xr, trow, xdrow, pr); break;
            case 14: p1_group<14>(xr, trow, xdrow, pr); break;
            default: p1_group<15>(xr, trow, xdrow, pr); break;
        }
    }

    // ---- per-wave descriptor preload into 2 VGPRs (lane = step - s0) ----
    const int c = kh * 8 + wave;                       // 16 global chunks
    const int s0 = __builtin_amdgcn_readfirstlane((c * NSTEPS) >> 4);
    const int s1 = __builtin_amdgcn_readfirstlane(((c + 1) * NSTEPS) >> 4);
    int didx = 2 * (s0 + lane);                        // < 2*(390+63)+1 < NDESC ok
    uint32_t vD0 = DESC_G.d[didx];
    uint32_t vD1 = DESC_G.d[didx + 1];

    __syncthreads();

    const char* trowB = (const char*)t + r * (TSTRIDE * 2);
    const char* xdrowB = (const char*)xd + r * (XDSTRIDE * 2);
    const char* wpB = (const char*)Wh + lane * 16;     // + s*1024 per step
    const uint32_t rx = (uint32_t)((r & 7) << 4);

    f32x16 acc0, acc1;
#pragma unroll
    for (int i = 0; i < 16; ++i) { acc0[i] = 0.0f; acc1[i] = 0.0f; }

#define DSEL(IDX) (hsel ? __builtin_amdgcn_readlane(vD1, (IDX)) \
                        : __builtin_amdgcn_readlane(vD0, (IDX)))

    // prologue: issue loads for steps s0, s0+1
    uint32_t dp0 = DSEL(0);
    uint32_t dp1 = DSEL(1);
    f16x8 araw0 = *(const f16x8*)(trowB + ((dp0 & 0xffffu) ^ rx));
    _Float16 xs0 = *(const _Float16*)(xdrowB + (dp0 >> 16));
    f16x8 araw1 = *(const f16x8*)(trowB + ((dp1 & 0xffffu) ^ rx));
    _Float16 xs1 = *(const _Float16*)(xdrowB + (dp1 >> 16));
    f16x8 breg0 = *(const f16x8*)(wpB + (size_t)s0 * 1024);
    f16x8 breg1 = *(const f16x8*)(wpB + (size_t)(s0 + 1) * 1024);

#define BODY(P, SCUR) do {                                                    \
    f16x8 xsv_ = { xs##P, xs##P, xs##P, xs##P, xs##P, xs##P, xs##P, xs##P };  \
    f16x8 a_ = araw##P * xsv_;                                                \
    f16x8 bu_ = breg##P;                                                      \
    uint32_t dn_ = DSEL((SCUR) + 2 - s0);                                     \
    araw##P = *(const f16x8*)(trowB + ((dn_ & 0xffffu) ^ rx));                \
    xs##P   = *(const _Float16*)(xdrowB + (dn_ >> 16));                       \
    breg##P = *(const f16x8*)(wpB + (size_t)((SCUR) + 2) * 1024);             \
    acc##P = __builtin_amdgcn_mfma_f32_32x32x16_f16(a_, bu_, acc##P, 0, 0, 0);\
} while (0)

    int s = s0;
    for (; s + 1 < s1; s += 2) { BODY(0, s); BODY(1, s + 1); }
    if (s < s1) {   // odd-length chunk tail (slot 0)
        f16x8 xsv_ = { xs0, xs0, xs0, xs0, xs0, xs0, xs0, xs0 };
        f16x8 a_ = araw0 * xsv_;
        acc0 = __builtin_amdgcn_mfma_f32_32x32x16_f16(a_, breg0, acc0, 0, 0, 0);
    }
#undef BODY
#undef DSEL

    // ---- epilogue: 8-bank LDS reduce (aliased over t), atomic combine ----
    __syncthreads();                                   // all waves done with t/xd
    float* red = (float*)smem;                         // 8 * 4096 B = 32768 B
    float* bank = red + wave * 1024;
#pragma unroll
    for (int reg = 0; reg < 16; ++reg) {
        int rr = (reg & 3) + 8 * (reg >> 2) + 4 * hsel;  // C/D row
        bank[rr * 32 + r] = acc0[reg] + acc1[reg];
    }
    __syncthreads();
    float* op = out + (size_t)mtile * 1024;
#pragma unroll
    for (int i = 0; i < 2; ++i) {
        int e = tid + i * 512;
        float v = red[e] + red[1024 + e] + red[2048 + e] + red[3072 + e]
                + red[4096 + e] + red[5120 + e] + red[6144 + e] + red[7168 + e];
        atomicAdd(op + e, v);
    }
}

extern "C" void kernel_launch(void* const* d_in, const int* in_sizes, int n_in,
                              void* d_out, int out_size, void* d_ws, size_t ws_size,
                              hipStream_t stream) {
    (void)in_sizes; (void)n_in; (void)out_size; (void)ws_size;
    const float* x = (const float*)d_in[0];   // [8192,32]
    const float* W = (const float*)d_in[1];   // [6545,32]
    float* out = (float*)d_out;               // [8192,32]
    _Float16* Wh = (_Float16*)d_ws;           // ~430 KB of d_ws used

    prep<<<361, 256, 0, stream>>>(x, W, out, Wh);
    gemm<<<512, 512, 0, stream>>>(x, Wh, out);
}

// Round 6
// 69.581 us; speedup vs baseline: 1.4159x; 1.0057x over previous
//
#include <hip/hip_runtime.h>
#include <cstdint>
#include <cstddef>
#include <utility>

// ---------------------------------------------------------------------------
// out[8192,32] = x + P(x)[8192,6545] @ W[6545,32]
// v6: uniform 28-step chunks + 4-deep rotating pipeline.
//   K padded to 448 steps (7168): 16 chunks x 28 steps exactly; pad steps have
//   zero descriptors (safe addrs) and zero W rows -> contribute 0.
//   Grid 512 x 512thr (2 blocks/mtile, K-split 2, 16 waves/CU).
//   Per wave: fully unrolled 7x4 BODYs, 4-slot pipeline (araw/xs/breg
//   prefetched 4 steps ahead -> ~160+ cyc slack covers LDS ~120 / L2 ~200).
//   Descs preloaded in 2 VGPRs, consumed via v_readlane w/ constant index.
//   Single f32x16 accumulator (saves 16 VGPRs; wave interleave covers MFMA
//   latency). Epilogue: 8-bank LDS reduce + atomicAdd (out=x from prep).
// ---------------------------------------------------------------------------

#define NF 32
#define NPOLY 6545
#define NSTEPS 448          // K = 7168 = 448*16 (zero-padded from 6545)
#define NREAL 417           // steps with any real data (417*16 = 6672)
#define NOCT 834            // real half-octet descriptors
#define NDESC 1024          // zero-padded (toff=0/xoff=0 -> safe addresses)
#define CHUNK 28            // steps per wave (16 chunks x 28 = 448)
#define TSTRIDE 576         // halfs per t-row (72 octets, 1152 B)
#define D2OFF 40            // d2 base index inside t (8-aligned)
#define XDSTRIDE 34         // halfs per xdup row (68 B)

#define XD_OFF    36864     // t = 32*576*2 bytes
#define SMEM_BYTES 39040    // t + xd

typedef _Float16 f16x8 __attribute__((ext_vector_type(8)));
typedef float f32x16 __attribute__((ext_vector_type(16)));

#define D2N 528
struct D2I { uint8_t a[D2N]; uint8_t b[D2N]; };
constexpr D2I build_d2i() {
    D2I t{};
    int k = 0;
    for (int f = 0; f < NF; ++f)
        for (int m = 0; m <= f; ++m) { t.a[k] = (uint8_t)f; t.b[k] = (uint8_t)m; ++k; }
    return t;
}
constexpr D2I D2T = build_d2i();

// Descriptor per half-octet: low16 = t byte offset (16B aligned), high16 = xd
// byte offset (xidx*2; xidx 0 -> 1.0, 1+f -> x_f). Zero-padded to NDESC.
struct Desc { uint32_t d[NDESC]; };
constexpr Desc build_desc() {
    Desc D{};
    int u = 0;
    for (int o = 0; o < 72; ++o)                       // segA: direct t octets
        D.d[u++] = (uint32_t)(o * 16);
    for (int f = 0; f < NF; ++f) {                     // segB: x_f * d2 octets
        int cnt = (f + 1) * (f + 2) / 2;
        for (int j8 = 0; j8 < (cnt + 7) / 8; ++j8)
            D.d[u++] = (uint32_t)((D2OFF + 8 * j8) * 2) | ((uint32_t)((1 + f) * 2) << 16);
    }
    while (u < NDESC) D.d[u++] = 0u;                   // pad: t[0..7] * xd[0]
    return D;
}
__device__ const Desc DESC_G = build_desc();

// Map new K index -> original monomial index (or -1 = zero W row).
struct Oldk { int16_t v[NSTEPS * 16]; };
constexpr Oldk build_oldk() {
    Oldk K{};
    int k = 0;
    for (int ti = 0; ti < 576; ++ti) {                 // segA
        int old;
        if (ti == 0) old = 0;
        else if (ti <= 32) old = ti;
        else if (ti >= D2OFF && ti < D2OFF + D2N) old = 33 + (ti - D2OFF);
        else old = -1;
        K.v[k++] = (int16_t)old;
    }
    for (int f = 0; f < NF; ++f) {                     // segB
        int cnt = (f + 1) * (f + 2) / 2;
        int off3 = 0;
        for (int g = 0; g < f; ++g) off3 += (g + 1) * (g + 2) / 2;
        int oc = (cnt + 7) / 8;
        for (int m = 0; m < oc * 8; ++m)
            K.v[k++] = (int16_t)(m < cnt ? 561 + off3 + m : -1);
    }
    while (k < NSTEPS * 16) K.v[k++] = (int16_t)-1;    // pad steps: zero W
    return K;
}
__device__ const Oldk OLDK_G = build_oldk();

// ---- phase-1 helpers ----
template<int TI>
__device__ __forceinline__ _Float16 tval(const float (&xr)[NF]) {
    if constexpr (TI == 0) return (_Float16)1.0f;
    else if constexpr (TI >= 1 && TI <= 32) return (_Float16)xr[TI - 1];
    else if constexpr (TI >= D2OFF && TI < D2OFF + D2N) {
        constexpr int m = TI - D2OFF;
        return (_Float16)(xr[D2T.a[m]] * xr[D2T.b[m]]);
    } else return (_Float16)0.0f;
}

template<int O, int... Js>
__device__ __forceinline__ void put_oct(std::integer_sequence<int, Js...>,
                                        const float (&xr)[NF], _Float16* trow, int r) {
    f16x8 v = { tval<O * 8 + Js>(xr)... };
    int slot = (O & ~7) | ((O ^ r) & 7);               // XOR swizzle (16B granule)
    *(f16x8*)(trow + slot * 8) = v;
}

template<int BASE, int... Os>
__device__ __forceinline__ void p1_octs(std::integer_sequence<int, Os...>,
                                        const float (&xr)[NF], _Float16* trow, int r) {
    (put_oct<BASE + Os>(std::make_integer_sequence<int, 8>{}, xr, trow, r), ...);
}

template<int V>
__device__ __forceinline__ void xdw(const float (&xr)[NF], _Float16* xdrow) {
    if constexpr (V == 0) xdrow[0] = (_Float16)1.0f;
    else if constexpr (V <= 32) xdrow[V] = (_Float16)xr[V - 1];
}

template<int G>
__device__ __forceinline__ void p1_group(const float (&xr)[NF], _Float16* trow,
                                         _Float16* xdrow, int r) {
    if constexpr (G < 8)
        p1_octs<G * 5>(std::make_integer_sequence<int, 5>{}, xr, trow, r);
    else
        p1_octs<40 + (G - 8) * 4>(std::make_integer_sequence<int, 4>{}, xr, trow, r);
    xdw<2 * G>(xr, xdrow);
    xdw<2 * G + 1>(xr, xdrow);
    if constexpr (G == 15) xdw<32>(xr, xdrow);
}

// ---- prep: out = x, and Wh = permuted/padded f16 W ([step][64 lanes][8]) ----
__global__ void prep(const float* __restrict__ x, const float* __restrict__ W,
                     float* __restrict__ out, _Float16* __restrict__ Wh) {
    int b = blockIdx.x;
    if (b < 256) {
        int id = b * 256 + threadIdx.x;                // 65536 float4
        ((float4*)out)[id] = ((const float4*)x)[id];
    } else {
        int id = (b - 256) * 256 + threadIdx.x;        // octet index
        if (id < NSTEPS * 64) {                        // 28672
            int step = id >> 6, rem = id & 63, hs = rem >> 5, n = rem & 31;
            int k0 = step * 16 + hs * 8;
            f16x8 v;
#pragma unroll
            for (int j = 0; j < 8; ++j) {
                int old = OLDK_G.v[k0 + j];
                v[j] = (_Float16)(old >= 0 ? W[old * 32 + n] : 0.0f);
            }
            *(f16x8*)(Wh + (size_t)id * 8) = v;
        }
    }
}

__global__ __launch_bounds__(512, 4) void gemm(const float* __restrict__ x,
                                               const _Float16* __restrict__ Wh,
                                               float* __restrict__ out) {
    __shared__ __align__(16) unsigned char smem[SMEM_BYTES];
    _Float16* t  = (_Float16*)smem;
    _Float16* xd = (_Float16*)(smem + XD_OFF);

    const int tid = threadIdx.x;
    const int wave = __builtin_amdgcn_readfirstlane(tid >> 6);
    const int lane = tid & 63;
    const int hsel = lane >> 5, r = lane & 31;
    const int mtile = blockIdx.x >> 1;
    const int kh = blockIdx.x & 1;

    // ---- phase 1: t (swizzled) + xdup ----
    {
        const int pr = tid & 31, g = tid >> 5;         // 16 workers per row
        float xr[NF];
        const float4* xp = (const float4*)(x + (size_t)(mtile * 32 + pr) * NF);
#pragma unroll
        for (int i = 0; i < 8; ++i) {
            float4 v = xp[i];
            xr[4 * i + 0] = v.x; xr[4 * i + 1] = v.y;
            xr[4 * i + 2] = v.z; xr[4 * i + 3] = v.w;
        }
        _Float16* trow = t + pr * TSTRIDE;
        _Float16* xdrow = xd + pr * XDSTRIDE;
        switch (g) {
            case  0: p1_group< 0>(xr, trow, xdrow, pr); break;
            case  1: p1_group< 1>(xr, trow, xdrow, pr); break;
            case  2: p1_group< 2>(xr, trow, xdrow, pr); break;
            case  3: p1_group< 3>(xr, trow, xdrow, pr); break;
            case  4: p1_group< 4>(xr, trow, xdrow, pr); break;
            case  5: p1_group< 5>(xr, trow, xdrow, pr); break;
            case  6: p1_group< 6>(xr, trow, xdrow, pr); break;
            case  7: p1_group< 7>(xr, trow, xdrow, pr); break;
            case  8: p1_group< 8>(xr, trow, xdrow, pr); break;
            case  9: p1_group< 9>(xr, trow, xdrow, pr); break;
            case 10: p1_group<10>(xr, trow, xdrow, pr); break;
            case 11: p1_group<11>(xr, trow, xdrow, pr); break;
            case 12: p1_group<12>(xr, trow, xdrow, pr); break;
            case 13: p1_group<13>(xr, trow, xdrow, pr); break;
            case 14: p1_group<14>(xr, trow, xdrow, pr); break;
            default: p1_group<15>(xr, trow, xdrow, pr); break;
        }
    }

    // ---- per-wave descriptor preload (lane = step - s0; only 0..31 used) ----
    const int c = kh * 8 + wave;                       // 16 chunks of 28 steps
    const int s0 = __builtin_amdgcn_readfirstlane(c * CHUNK);
    uint32_t vD0 = DESC_G.d[2 * (s0 + lane)];          // max idx 2*(420+63)=966 < 1024
    uint32_t vD1 = DESC_G.d[2 * (s0 + lane) + 1];

    __syncthreads();

    const char* trowB = (const char*)t + r * (TSTRIDE * 2);
    const char* xdrowB = (const char*)xd + r * (XDSTRIDE * 2);
    const char* wpB = (const char*)Wh + lane * 16;     // + s*1024 per step
    const uint32_t rx = (uint32_t)((r & 7) << 4);

    f32x16 acc;
#pragma unroll
    for (int i = 0; i < 16; ++i) acc[i] = 0.0f;

#define DSEL(IDX) (hsel ? __builtin_amdgcn_readlane(vD1, (IDX)) \
                        : __builtin_amdgcn_readlane(vD0, (IDX)))

    f16x8 araw0, araw1, araw2, araw3;
    f16x8 breg0, breg1, breg2, breg3;
    _Float16 xs0, xs1, xs2, xs3;

#define LOADSLOT(P, IDX) do {                                                 \
    uint32_t d_ = DSEL(IDX);                                                  \
    araw##P = *(const f16x8*)(trowB + ((d_ & 0xffffu) ^ rx));                 \
    xs##P   = *(const _Float16*)(xdrowB + (d_ >> 16));                        \
    breg##P = *(const f16x8*)(wpB + (size_t)(s0 + (IDX)) * 1024);             \
} while (0)

    LOADSLOT(0, 0); LOADSLOT(1, 1); LOADSLOT(2, 2); LOADSLOT(3, 3);

#define BODY(P, IDX) do {                                                     \
    f16x8 xsv_ = { xs##P, xs##P, xs##P, xs##P, xs##P, xs##P, xs##P, xs##P };  \
    f16x8 a_ = araw##P * xsv_;                                                \
    f16x8 bu_ = breg##P;                                                      \
    LOADSLOT(P, (IDX) + 4);  /* prefetch 4 ahead; pads/over-reads are safe */ \
    acc = __builtin_amdgcn_mfma_f32_32x32x16_f16(a_, bu_, acc, 0, 0, 0);      \
} while (0)

#pragma unroll
    for (int i = 0; i < 7; ++i) {
        BODY(0, 4 * i + 0);
        BODY(1, 4 * i + 1);
        BODY(2, 4 * i + 2);
        BODY(3, 4 * i + 3);
    }
#undef BODY
#undef LOADSLOT
#undef DSEL

    // ---- epilogue: 8-bank LDS reduce (aliased over t), atomic combine ----
    __syncthreads();                                   // all waves done with t/xd
    float* red = (float*)smem;                         // 8 * 4096 B = 32768 B
    float* bank = red + wave * 1024;
#pragma unroll
    for (int reg = 0; reg < 16; ++reg) {
        int rr = (reg & 3) + 8 * (reg >> 2) + 4 * hsel;  // C/D row
        bank[rr * 32 + r] = acc[reg];
    }
    __syncthreads();
    float* op = out + (size_t)mtile * 1024;
#pragma unroll
    for (int i = 0; i < 2; ++i) {
        int e = tid + i * 512;
        float v = red[e] + red[1024 + e] + red[2048 + e] + red[3072 + e]
                + red[4096 + e] + red[5120 + e] + red[6144 + e] + red[7168 + e];
        atomicAdd(op + e, v);
    }
}

extern "C" void kernel_launch(void* const* d_in, const int* in_sizes, int n_in,
                              void* d_out, int out_size, void* d_ws, size_t ws_size,
                              hipStream_t stream) {
    (void)in_sizes; (void)n_in; (void)out_size; (void)ws_size;
    const float* x = (const float*)d_in[0];   // [8192,32]
    const float* W = (const float*)d_in[1];   // [6545,32]
    float* out = (float*)d_out;               // [8192,32]
    _Float16* Wh = (_Float16*)d_ws;           // ~459 KB of d_ws used (incl over-read)

    prep<<<368, 256, 0, stream>>>(x, W, out, Wh);
    gemm<<<512, 512, 0, stream>>>(x, Wh, out);
}